// Round 10
// baseline (1496.147 us; speedup 1.0000x reference)
//
#include <hip/hip_runtime.h>

constexpr int N_NODES = 50000;
constexpr int N_EDGES = 1600000;
constexpr int NREL    = 12;
constexpr int F_INPUT = 64;
constexpr int HID     = 128;
constexpr int NCLS    = 10;
constexpr int NGRAPH  = 256;
constexpr float BN_EPS = 1e-5f;

// counting-sort CSR parameters
constexpr int NB    = 391;                    // buckets of 128 nodes (dst >> 7)
constexpr int SEGB  = 128 * NREL;             // 1536 segments per bucket (rel-major)
constexpr int NOFF  = NB * SEGB;              // segment offsets (+1 sentinel)
constexpr int NSTRIPL = 3125;                 // 50000/16 exact strips of 16 nodes
constexpr int NBLK  = 392;                    // partition blocks
constexpr int PTPB  = 1024;
constexpr int EPB   = 4096;                   // edges per partition block (4/thread)

typedef float v4f __attribute__((ext_vector_type(4)));
typedef short s8b __attribute__((ext_vector_type(8)));

__device__ __forceinline__ unsigned f2bf(float f) {
    unsigned u = __float_as_uint(f);
    return (u + 0x7FFFu + ((u >> 16) & 1u)) >> 16;   // RNE fp32->bf16
}
__device__ __forceinline__ unsigned pack2(float a, float b) {
    return f2bf(a) | (f2bf(b) << 16);
}
__device__ __forceinline__ float bflo(unsigned u) { return __uint_as_float(u << 16); }
__device__ __forceinline__ float bfhi(unsigned u) { return __uint_as_float(u & 0xFFFF0000u); }

// ---------------- fused prep: zero scratch + pack weights + cast x + pcnt ----------------
constexpr int PQ0 = 64;                        // bn1: 256 floats (uint4)
constexpr int PQ1 = PQ0 + 64;                  // bn2
constexpr int PQ2 = PQ1 + 8192;                // psum: 32768 floats
constexpr int PQ3 = PQ2 + 13 * F_INPUT * HID;  // pack_w1
constexpr int PQ4 = PQ3 + 13 * HID * HID;      // pack_w2
constexpr int PQ5 = PQ4 + N_NODES * F_INPUT / 4; // cast x (float4)
constexpr int PQ6 = PQ5 + NGRAPH;              // pcnt binary search
constexpr int PREP_BLOCKS = (PQ6 + 255) / 256;

__global__ void prep(const float* __restrict__ Wrel1, const float* __restrict__ root1,
                     const float* __restrict__ Wrel2, const float* __restrict__ root2,
                     const float* __restrict__ x, const int* __restrict__ batch,
                     ushort* __restrict__ Wp1, ushort* __restrict__ Wp2,
                     ushort* __restrict__ xb,
                     float* __restrict__ bn1, float* __restrict__ bn2,
                     float* __restrict__ psum, float* __restrict__ pcnt) {
    int tid = blockIdx.x * 256 + threadIdx.x;
    const uint4 z = make_uint4(0, 0, 0, 0);
    if (tid < PQ0) { reinterpret_cast<uint4*>(bn1)[tid] = z; return; }
    if (tid < PQ1) { reinterpret_cast<uint4*>(bn2)[tid - PQ0] = z; return; }
    if (tid < PQ2) { reinterpret_cast<uint4*>(psum)[tid - PQ1] = z; return; }
    if (tid < PQ3) {
        int idx = tid - PQ2;                       // 13 * 8192
        int r = idx >> 13, rem = idx & 8191;
        int k = rem >> 7, n = rem & 127;
        const float* W = (r < NREL) ? (Wrel1 + (size_t)r * 8192) : root1;
        float v = W[k * HID + n];
        int b = k >> 5, kk = k & 31;
        int j = (n & 7) * 16 + (n >> 3);           // col-permuted fragment row
        Wp1[(((size_t)(r * 2 + b)) * HID + j) * 32 + kk] = (ushort)f2bf(v);
        return;
    }
    if (tid < PQ4) {
        int idx = tid - PQ3;                       // 13 * 16384
        int r = idx >> 14, rem = idx & 16383;
        int k = rem >> 7, n = rem & 127;
        const float* W = (r < NREL) ? (Wrel2 + (size_t)r * 16384) : root2;
        float v = W[k * HID + n];
        int b = k >> 5, kk = k & 31;
        int j = (n & 7) * 16 + (n >> 3);
        Wp2[(((size_t)(r * 4 + b)) * HID + j) * 32 + kk] = (ushort)f2bf(v);
        return;
    }
    if (tid < PQ5) {
        int i = tid - PQ4;
        float4 v = reinterpret_cast<const float4*>(x)[i];
        uint2 o;
        o.x = pack2(v.x, v.y);
        o.y = pack2(v.z, v.w);
        reinterpret_cast<uint2*>(xb)[i] = o;
        return;
    }
    if (tid < PQ6) {
        int g = tid - PQ5;
        int lo0 = 0, hi0 = N_NODES;
        while (lo0 < hi0) { int m = (lo0 + hi0) >> 1; if (batch[m] < g) lo0 = m + 1; else hi0 = m; }
        int lo1 = lo0, hi1 = N_NODES;
        while (lo1 < hi1) { int m = (lo1 + hi1) >> 1; if (batch[m] < g + 1) lo1 = m + 1; else hi1 = m; }
        pcnt[g] = (float)(lo1 - lo0);
    }
}

// ---------------- counting-sort CSR build (no far atomics) ----------------

__global__ __launch_bounds__(PTPB)
void part_hist(const int* __restrict__ dst, int* __restrict__ histG) {
    __shared__ int h[NB];
    int t = threadIdx.x, blk = blockIdx.x;
    if (t < NB) h[t] = 0;
    __syncthreads();
    int base = blk * EPB;
#pragma unroll
    for (int it = 0; it < EPB / PTPB; ++it) {
        int e = base + it * PTPB + t;
        if (e < N_EDGES) atomicAdd(&h[dst[e] >> 7], 1);
    }
    __syncthreads();
    if (t < NB) histG[blk * NB + t] = h[t];
}

__global__ __launch_bounds__(512)
void part_scanA(const int* __restrict__ histG, int* __restrict__ cursorG,
                int* __restrict__ bucketTot) {
    __shared__ int s[512];
    int t = threadIdx.x, b = blockIdx.x;
    int v = (t < NBLK) ? histG[t * NB + b] : 0;
    s[t] = v;
    __syncthreads();
    for (int d = 1; d < 512; d <<= 1) {
        int x = (t >= d) ? s[t - d] : 0;
        __syncthreads();
        s[t] += x;
        __syncthreads();
    }
    if (t < NBLK) cursorG[t * NB + b] = s[t] - v;   // exclusive prefix
    if (t == NBLK - 1) bucketTot[b] = s[t];
}

__global__ __launch_bounds__(512)
void part_scanB(const int* __restrict__ bucketTot, int* __restrict__ bucketBase) {
    __shared__ int s[512];
    int t = threadIdx.x;
    int v = (t < NB) ? bucketTot[t] : 0;
    s[t] = v;
    __syncthreads();
    for (int d = 1; d < 512; d <<= 1) {
        int x = (t >= d) ? s[t - d] : 0;
        __syncthreads();
        s[t] += x;
        __syncthreads();
    }
    if (t <= NB) bucketBase[t] = (t == 0) ? 0 : s[t - 1];
}

__global__ __launch_bounds__(PTPB)
void part_scatter(const int* __restrict__ src, const int* __restrict__ dst,
                  const int* __restrict__ et, const int* __restrict__ cursorG,
                  const int* __restrict__ bucketBase, uint* __restrict__ ebuck) {
    __shared__ int cur[NB];
    int t = threadIdx.x, blk = blockIdx.x;
    if (t < NB) cur[t] = cursorG[blk * NB + t] + bucketBase[t];
    __syncthreads();
    int base = blk * EPB;
#pragma unroll
    for (int it = 0; it < EPB / PTPB; ++it) {
        int e = base + it * PTPB + t;
        if (e < N_EDGES) {
            int d = dst[e];
            int b = d >> 7;
            int pos = atomicAdd(&cur[b], 1);
            ebuck[pos] = (uint)src[e] | ((uint)(d & 127) << 16) | ((uint)et[e] << 23);
        }
    }
}

// P4: per-bucket finalize, REL-MAJOR key: edge list sorted by (bucket, rel, localnode).
// zpack[e] = src | (localnode << 16) -> fused build detects node boundaries
// from the stream itself (no offset pointer-chase in the inner loop).
__global__ __launch_bounds__(256)
void csr_finalize(const uint* __restrict__ ebuck, const int* __restrict__ bucketBase,
                  int* __restrict__ off, uint* __restrict__ zpack) {
    __shared__ int cnt[SEGB];
    __shared__ int cur[SEGB];
    __shared__ int partial[256];
    int t = threadIdx.x, b = blockIdx.x;
    int eb0 = bucketBase[b], eb1 = bucketBase[b + 1];
#pragma unroll
    for (int i = 0; i < 6; ++i) cnt[t * 6 + i] = 0;
    __syncthreads();
    for (int e = eb0 + t; e < eb1; e += 256) {
        uint u = ebuck[e];
        int key = (int)(u >> 23) * 128 + (int)((u >> 16) & 127);   // rel-major
        atomicAdd(&cnt[key], 1);
    }
    __syncthreads();
    int loc[6];
    int sum = 0;
#pragma unroll
    for (int i = 0; i < 6; ++i) { loc[i] = sum; sum += cnt[t * 6 + i]; }
    partial[t] = sum;
    __syncthreads();
    for (int d = 1; d < 256; d <<= 1) {
        int v = (t >= d) ? partial[t - d] : 0;
        __syncthreads();
        partial[t] += v;
        __syncthreads();
    }
    int tbase = (t == 0) ? 0 : partial[t - 1];
#pragma unroll
    for (int i = 0; i < 6; ++i) {
        int s = t * 6 + i;
        int gpos = eb0 + tbase + loc[i];
        cur[s] = gpos;
        off[b * SEGB + s] = gpos;      // all 1536 keys (empty -> zero-length)
    }
    __syncthreads();
    for (int e = eb0 + t; e < eb1; e += 256) {
        uint u = ebuck[e];
        int key = (int)(u >> 23) * 128 + (int)((u >> 16) & 127);
        int pos = atomicAdd(&cur[key], 1);
        zpack[pos] = u & 0x7FFFFFu;                // src(16) | localnode(7)
    }
    if (b == 0 && t == 0) off[NOFF] = N_EDGES;
}

// ---------------- FUSED mean-aggregate + concatenated-K GEMM, in-block rel-split --------
// One block per 16-node STRIP (grid 3125), 4 waves; wave w handles rels
// {3w..3w+2} (wave 3: +root). CH=8 clamped chunks, one-chunk zpack prefetch.
// launch_bounds(256,6): the r6-PROVEN envelope (164 us @ 53% occ for F=128).
// r7 (lb 256,8 -> VGPR=32) spilled 375 MB, 4.4x slower; r8 (CH=4) halved the
// gather ILP, 4x slower at same occupancy. CH=8 + lb(256,6) is the verified
// optimum of this structure; only delta vs r6: BN partial stats fused into
// the wave0 epilogue (drops two 25.6 MB bn_stats passes).

template <int F>
__global__ __launch_bounds__(256, 6)
void gemm_fused(const ushort* __restrict__ X, const int* __restrict__ offR,
                const uint* __restrict__ zpack, const ushort* __restrict__ Wp,
                const float* __restrict__ bias, float* __restrict__ H,
                float* __restrict__ bn_sum, float* __restrict__ bn_sq) {
    constexpr int FP2 = F + 8;
    constexpr int KB  = F / 32;
    constexpr int CH  = 8;                            // edges per chunk (r6-proven ILP)
    constexpr int ABYTES = 4 * 16 * FP2 * 2;          // 4 per-wave A strips
    constexpr int RBYTES = 2 * 16 * HID * 4;          // 16 KB: two fp32 partials
    constexpr int LBYTES = (ABYTES > RBYTES) ? ABYTES : RBYTES;
    __shared__ __align__(16) char LDSU[LBYTES];
    const int t = threadIdx.x;
    const int lane = t & 63, wave = t >> 6, q = lane >> 4, l16 = lane & 15;
    const int strip = blockIdx.x;                      // [0, 3125)
    const int bucket = strip >> 3;
    const int rowbase = (strip & 7) * 16;
    const int n0 = strip * 16;                         // first global node
    const int obase = bucket * SEGB + rowbase;
    ushort* Ab = reinterpret_cast<ushort*>(LDSU) + wave * 16 * FP2;

    auto zerorow = [&](int r) {
        if constexpr (F == 64) Ab[r * FP2 + lane] = 0;
        else *reinterpret_cast<uint*>(Ab + r * FP2 + lane * 2) = 0u;
    };

    auto buildrel = [&](int rel) -> bool {
        const int i0 = obase + rel * 128;
        const int e0 = offR[i0];
        const int e1 = offR[i0 + 16];
        if (e0 >= e1) return false;                     // empty: skip MFMA entirely
        const int elast = e1 - 1;
        float a0 = 0.f, a1 = 0.f;
        int ln = 0, eStart = e0;
        auto flush = [&](int r, int cntE) {
            float winv = (cntE > 0) ? 1.f / (float)cntE : 0.f;
            if constexpr (F == 64)
                Ab[r * FP2 + lane] = (ushort)f2bf(a0 * winv);
            else
                *reinterpret_cast<uint*>(Ab + r * FP2 + lane * 2) = pack2(a0 * winv, a1 * winv);
            a0 = 0.f; a1 = 0.f;
        };
        auto ldpk = [&](int e, uint* p) {
#pragma unroll
            for (int j = 0; j < CH; ++j) p[j] = zpack[min(e + j, elast)];
        };
        uint pk[CH];
        ldpk(e0, pk);
        for (int e = e0; e < e1; e += CH) {
            uint ux[CH];
#pragma unroll
            for (int j = 0; j < CH; ++j) {              // 8 independent gathers
                int s = (int)(pk[j] & 0xFFFFu);
                if constexpr (F == 64)
                    ux[j] = X[(size_t)s * 64 + lane];
                else
                    ux[j] = *reinterpret_cast<const uint*>(X + (size_t)s * 128 + lane * 2);
            }
            uint pkn[CH];
            ldpk(e + CH, pkn);                          // clamped -> always safe
#pragma unroll
            for (int j = 0; j < CH; ++j) {
                int ej = e + j;
                if (ej < e1) {                          // wave-uniform
                    int ld = (int)(pk[j] >> 16) - rowbase;
                    if (ld != ln) {                     // node boundary from stream
                        flush(ln, ej - eStart);
                        for (int z = ln + 1; z < ld; ++z) zerorow(z);
                        ln = ld; eStart = ej;
                    }
                    a0 += bflo(ux[j]);
                    if constexpr (F == 128) a1 += bfhi(ux[j]);
                }
            }
#pragma unroll
            for (int j = 0; j < CH; ++j) pk[j] = pkn[j];
        }
        flush(ln, e1 - eStart);
        for (int z = ln + 1; z < 16; ++z) zerorow(z);
        return true;
    };

    v4f acc[8];
#pragma unroll
    for (int nt = 0; nt < 8; ++nt) acc[nt] = (v4f){0.f, 0.f, 0.f, 0.f};

    const int r0 = wave * 3;
    const int r1 = (wave == 3) ? 13 : (r0 + 3);
    for (int rel = r0; rel < r1; ++rel) {
        bool have;
        if (rel == NREL) {                  // root block: direct copy of X rows
#pragma unroll 4
            for (int i = 0; i < 16; ++i) {
                int n = n0 + i;
                if constexpr (F == 64) {
                    Ab[i * FP2 + lane] = (n < N_NODES) ? X[(size_t)n * 64 + lane] : (ushort)0;
                } else {
                    uint v = (n < N_NODES)
                        ? *reinterpret_cast<const uint*>(X + (size_t)n * 128 + lane * 2) : 0u;
                    *reinterpret_cast<uint*>(Ab + i * FP2 + lane * 2) = v;
                }
            }
            have = true;
        } else {
            have = buildrel(rel);
        }
        if (have) {
#pragma unroll
            for (int kb = 0; kb < KB; ++kb) {
                s8b bfr[8];
                const ushort* wb = Wp + ((size_t)(rel * KB + kb) * HID + l16) * 32 + q * 8;
#pragma unroll
                for (int nt = 0; nt < 8; ++nt)
                    bfr[nt] = *reinterpret_cast<const s8b*>(wb + (size_t)nt * 16 * 32);
                s8b af = *reinterpret_cast<const s8b*>(Ab + l16 * FP2 + kb * 32 + q * 8);
#pragma unroll
                for (int nt = 0; nt < 8; ++nt)
                    acc[nt] = __builtin_amdgcn_mfma_f32_16x16x32_bf16(af, bfr[nt], acc[nt], 0, 0, 0);
            }
        }
    }

    // ---- pairwise cross-wave combine in LDS (A memory dead), wave0 writes H + bias ----
    const int c0 = l16 * 8;    // lane l16 owns logical cols c0..c0+7 (Wp is col-permuted)
    float* red = reinterpret_cast<float*>(LDSU);
    __syncthreads();                       // all MFMA reads of A complete
    if (wave >= 2) {
        float* rw = red + (size_t)(wave - 2) * 16 * HID;
#pragma unroll
        for (int rr = 0; rr < 4; ++rr) {
            int row = q * 4 + rr;
            *reinterpret_cast<float4*>(rw + row * HID + c0) =
                make_float4(acc[0][rr], acc[1][rr], acc[2][rr], acc[3][rr]);
            *reinterpret_cast<float4*>(rw + row * HID + c0 + 4) =
                make_float4(acc[4][rr], acc[5][rr], acc[6][rr], acc[7][rr]);
        }
    }
    __syncthreads();
    if (wave < 2) {
        const float* rw = red + (size_t)wave * 16 * HID;
#pragma unroll
        for (int rr = 0; rr < 4; ++rr) {
            int row = q * 4 + rr;
            float4 a0 = *reinterpret_cast<const float4*>(rw + row * HID + c0);
            float4 a1 = *reinterpret_cast<const float4*>(rw + row * HID + c0 + 4);
            acc[0][rr] += a0.x; acc[1][rr] += a0.y; acc[2][rr] += a0.z; acc[3][rr] += a0.w;
            acc[4][rr] += a1.x; acc[5][rr] += a1.y; acc[6][rr] += a1.z; acc[7][rr] += a1.w;
        }
    }
    __syncthreads();
    if (wave == 1) {
#pragma unroll
        for (int rr = 0; rr < 4; ++rr) {
            int row = q * 4 + rr;
            *reinterpret_cast<float4*>(red + row * HID + c0) =
                make_float4(acc[0][rr], acc[1][rr], acc[2][rr], acc[3][rr]);
            *reinterpret_cast<float4*>(red + row * HID + c0 + 4) =
                make_float4(acc[4][rr], acc[5][rr], acc[6][rr], acc[7][rr]);
        }
    }
    __syncthreads();
    if (wave == 0) {
        float4 b4a = *reinterpret_cast<const float4*>(bias + c0);
        float4 b4b = *reinterpret_cast<const float4*>(bias + c0 + 4);
        float bv[8] = {b4a.x, b4a.y, b4a.z, b4a.w, b4b.x, b4b.y, b4b.z, b4b.w};
        float s[8], sq[8];
#pragma unroll
        for (int nt = 0; nt < 8; ++nt) { s[nt] = 0.f; sq[nt] = 0.f; }
#pragma unroll
        for (int rr = 0; rr < 4; ++rr) {
            int row = q * 4 + rr;
            int n = n0 + row;                          // grid exact: always < N_NODES
            const float* rw = red + row * HID + c0;
            float4 a0 = *reinterpret_cast<const float4*>(rw);
            float4 a1 = *reinterpret_cast<const float4*>(rw + 4);
            float v[8];
            v[0] = acc[0][rr] + a0.x + bv[0];
            v[1] = acc[1][rr] + a0.y + bv[1];
            v[2] = acc[2][rr] + a0.z + bv[2];
            v[3] = acc[3][rr] + a0.w + bv[3];
            v[4] = acc[4][rr] + a1.x + bv[4];
            v[5] = acc[5][rr] + a1.y + bv[5];
            v[6] = acc[6][rr] + a1.z + bv[6];
            v[7] = acc[7][rr] + a1.w + bv[7];
#pragma unroll
            for (int nt = 0; nt < 8; ++nt) {
                s[nt] += v[nt];
                sq[nt] += v[nt] * v[nt];
            }
            float* hr = H + (size_t)n * HID + c0;
            *reinterpret_cast<float4*>(hr)     = make_float4(v[0], v[1], v[2], v[3]);
            *reinterpret_cast<float4*>(hr + 4) = make_float4(v[4], v[5], v[6], v[7]);
        }
        // strip BN partials: reduce across q (lanes l16, +16, +32, +48), one atomic/col
#pragma unroll
        for (int nt = 0; nt < 8; ++nt) {
            s[nt]  += __shfl_xor(s[nt], 16);  s[nt]  += __shfl_xor(s[nt], 32);
            sq[nt] += __shfl_xor(sq[nt], 16); sq[nt] += __shfl_xor(sq[nt], 32);
        }
        if (q == 0) {
#pragma unroll
            for (int nt = 0; nt < 8; ++nt) {
                atomicAdd(&bn_sum[c0 + nt], s[nt]);
                atomicAdd(&bn_sq[c0 + nt], sq[nt]);
            }
        }
    }
}

// ---------------- BN(+finalize) + ReLU, emit bf16 ----------------

__global__ void bn_relu_bf16(const float* __restrict__ h, const float* __restrict__ bn_sum,
                             const float* __restrict__ bn_sq, const float* __restrict__ gamma,
                             const float* __restrict__ beta, ushort* __restrict__ outb) {
    __shared__ float CA[HID], CB[HID];
    int t = threadIdx.x;
    if (t < HID) {
        float mu = bn_sum[t] * (1.0f / N_NODES);
        float var = bn_sq[t] * (1.0f / N_NODES) - mu * mu;
        float a = gamma[t] / sqrtf(var + BN_EPS);
        CA[t] = a;
        CB[t] = beta[t] - a * mu;
    }
    __syncthreads();
    int i = blockIdx.x * 256 + t;  // float4 index
    constexpr int TOTAL = N_NODES * HID / 4;
    if (i < TOTAL) {
        int o4 = i & 31;
        float4 a = reinterpret_cast<const float4*>(CA)[o4];
        float4 b = reinterpret_cast<const float4*>(CB)[o4];
        float4 v = reinterpret_cast<const float4*>(h)[i];
        v.x = fmaxf(a.x * v.x + b.x, 0.f);
        v.y = fmaxf(a.y * v.y + b.y, 0.f);
        v.z = fmaxf(a.z * v.z + b.z, 0.f);
        v.w = fmaxf(a.w * v.w + b.w, 0.f);
        uint2 o;
        o.x = pack2(v.x, v.y);
        o.y = pack2(v.z, v.w);
        reinterpret_cast<uint2*>(outb)[i] = o;
    }
}

// ---------------- pooling (BN finalize + ReLU fused; batch sorted -> run-length) ----------------

__global__ void pool_bnrelu(const float* __restrict__ h, const float* __restrict__ bn_sum,
                            const float* __restrict__ bn_sq, const float* __restrict__ gamma,
                            const float* __restrict__ beta, const int* __restrict__ batch,
                            float* __restrict__ psum) {
    __shared__ float CA[HID], CB[HID];
    int t = threadIdx.x;
    if (t < HID) {
        float mu = bn_sum[t] * (1.0f / N_NODES);
        float var = bn_sq[t] * (1.0f / N_NODES) - mu * mu;
        float a = gamma[t] / sqrtf(var + BN_EPS);
        CA[t] = a;
        CB[t] = beta[t] - a * mu;
    }
    __syncthreads();
    int col = t & 127;
    int nb = blockIdx.x * 16 + (t >> 7) * 8;  // 8 consecutive nodes per thread
    float a = CA[col], b = CB[col];
    float run = 0.f;
    int curg = -1;
    for (int i = 0; i < 8; ++i) {
        int n = nb + i;
        if (n < N_NODES) {
            int g = batch[n];
            float v = fmaxf(a * h[(size_t)n * HID + col] + b, 0.f);
            if (g != curg) {
                if (curg >= 0) atomicAdd(&psum[curg * HID + col], run);
                run = 0.f;
                curg = g;
            }
            run += v;
        }
    }
    if (curg >= 0) atomicAdd(&psum[curg * HID + col], run);
}

__global__ void final_kernel(const float* __restrict__ psum, const float* __restrict__ pcnt,
                             const float* __restrict__ Wf, const float* __restrict__ bf,
                             float* __restrict__ out) {
    __shared__ float p[HID];
    int g = blockIdx.x, t = threadIdx.x;  // 64 threads
    float inv = 1.0f / fmaxf(pcnt[g], 1.0f);
    p[t] = psum[g * HID + t] * inv;
    p[t + 64] = psum[g * HID + t + 64] * inv;
    __syncthreads();
    if (t < NCLS) {
        float s = bf[t];
#pragma unroll 16
        for (int k = 0; k < HID; ++k) s += p[k] * Wf[k * NCLS + t];
        out[g * NCLS + t] = s;
    }
}

// ---------------- launch ----------------

extern "C" void kernel_launch(void* const* d_in, const int* in_sizes, int n_in,
                              void* d_out, int out_size, void* d_ws, size_t ws_size,
                              hipStream_t stream) {
    const float* x      = (const float*)d_in[0];
    const float* Wrel1  = (const float*)d_in[1];
    const float* root1  = (const float*)d_in[2];
    const float* bias1  = (const float*)d_in[3];
    const float* gamma1 = (const float*)d_in[4];
    const float* beta1  = (const float*)d_in[5];
    const float* Wrel2  = (const float*)d_in[6];
    const float* root2  = (const float*)d_in[7];
    const float* bias2  = (const float*)d_in[8];
    const float* gamma2 = (const float*)d_in[9];
    const float* beta2  = (const float*)d_in[10];
    const float* Wf     = (const float*)d_in[11];
    const float* bf     = (const float*)d_in[12];
    const int* ei       = (const int*)d_in[13];
    const int* et       = (const int*)d_in[14];
    const int* batch    = (const int*)d_in[15];
    const int* srcv = ei;
    const int* dstv = ei + N_EDGES;

    char* w = (char*)d_ws;
    auto alloc = [&](size_t bytes) -> char* {
        char* p = w;
        w += (bytes + 255) / 256 * 256;
        return p;
    };
    int* off     = (int*)alloc((size_t)(NOFF + 1) * 4);        // rel-major segment offsets
    uint* zpack  = (uint*)alloc((size_t)N_EDGES * 4);          // src | localnode<<16
    ushort* xb   = (ushort*)alloc((size_t)N_NODES * F_INPUT * 2);
    ushort* H1b  = (ushort*)alloc((size_t)N_NODES * HID * 2);
    ushort* Wp1  = (ushort*)alloc((size_t)13 * F_INPUT * HID * 2);
    ushort* Wp2  = (ushort*)alloc((size_t)13 * HID * HID * 2);
    float* bn1   = (float*)alloc(2 * HID * 4);  // sum | sq
    float* bn2   = (float*)alloc(2 * HID * 4);
    float* psum  = (float*)alloc((size_t)NGRAPH * HID * 4);
    float* pcnt  = (float*)alloc((size_t)NGRAPH * 4);
    float* Hbuf  = (float*)alloc((size_t)N_NODES * HID * 4);   // H1, later H2
    int* histG      = (int*)alloc((size_t)NBLK * NB * 4);
    int* cursorG    = (int*)alloc((size_t)NBLK * NB * 4);
    int* bucketTot  = (int*)alloc((size_t)NB * 4);
    int* bucketBase = (int*)alloc((size_t)(NB + 1) * 4);
    uint* ebuck     = (uint*)alloc((size_t)N_EDGES * 4);

    prep<<<PREP_BLOCKS, 256, 0, stream>>>(Wrel1, root1, Wrel2, root2, x, batch,
                                          Wp1, Wp2, xb, bn1, bn2, psum, pcnt);

    part_hist<<<NBLK, PTPB, 0, stream>>>(dstv, histG);
    part_scanA<<<NB, 512, 0, stream>>>(histG, cursorG, bucketTot);
    part_scanB<<<1, 512, 0, stream>>>(bucketTot, bucketBase);
    part_scatter<<<NBLK, PTPB, 0, stream>>>(srcv, dstv, et, cursorG, bucketBase, ebuck);
    csr_finalize<<<NB, 256, 0, stream>>>(ebuck, bucketBase, off, zpack);

    // ---- layer 1 (fused aggregate+GEMM+BN-stats, in-block rel-split) ----
    gemm_fused<F_INPUT><<<NSTRIPL, 256, 0, stream>>>(xb, off, zpack, Wp1, bias1,
                                                     Hbuf, bn1, bn1 + HID);
    bn_relu_bf16<<<(N_NODES * HID / 4 + 255) / 256, 256, 0, stream>>>(Hbuf, bn1, bn1 + HID,
                                                                      gamma1, beta1, H1b);

    // ---- layer 2 ----
    gemm_fused<HID><<<NSTRIPL, 256, 0, stream>>>(H1b, off, zpack, Wp2, bias2,
                                                 Hbuf, bn2, bn2 + HID);

    pool_bnrelu<<<(N_NODES + 15) / 16, 256, 0, stream>>>(Hbuf, bn2, bn2 + HID, gamma2, beta2,
                                                         batch, psum);
    final_kernel<<<NGRAPH, 64, 0, stream>>>(psum, pcnt, Wf, bf, (float*)d_out);
}

// Round 11
// 471.998 us; speedup vs baseline: 3.1698x; 3.1698x over previous
//
#include <hip/hip_runtime.h>

constexpr int N_NODES = 50000;
constexpr int N_EDGES = 1600000;
constexpr int NREL    = 12;
constexpr int F_INPUT = 64;
constexpr int HID     = 128;
constexpr int NCLS    = 10;
constexpr int NGRAPH  = 256;
constexpr float BN_EPS = 1e-5f;

// counting-sort CSR parameters
constexpr int NB    = 391;                    // buckets of 128 nodes (dst >> 7)
constexpr int SEGB  = 128 * NREL;             // 1536 segments per bucket (rel-major)
constexpr int NOFF  = NB * SEGB;              // segment offsets (+1 sentinel)
constexpr int NSTRIPL = 3125;                 // 50000/16 exact strips of 16 nodes
constexpr int NBLK  = 392;                    // partition blocks
constexpr int PTPB  = 1024;
constexpr int EPB   = 4096;                   // edges per partition block (4/thread)

typedef float v4f __attribute__((ext_vector_type(4)));
typedef short s8b __attribute__((ext_vector_type(8)));

__device__ __forceinline__ unsigned f2bf(float f) {
    unsigned u = __float_as_uint(f);
    return (u + 0x7FFFu + ((u >> 16) & 1u)) >> 16;   // RNE fp32->bf16
}
__device__ __forceinline__ unsigned pack2(float a, float b) {
    return f2bf(a) | (f2bf(b) << 16);
}
__device__ __forceinline__ float bflo(unsigned u) { return __uint_as_float(u << 16); }
__device__ __forceinline__ float bfhi(unsigned u) { return __uint_as_float(u & 0xFFFF0000u); }

// ---------------- fused prep: zero scratch + pack weights + cast x + pcnt ----------------
constexpr int PQ0 = 64;                        // bn1: 256 floats (uint4)
constexpr int PQ1 = PQ0 + 64;                  // bn2
constexpr int PQ2 = PQ1 + 8192;                // psum: 32768 floats
constexpr int PQ3 = PQ2 + 13 * F_INPUT * HID;  // pack_w1
constexpr int PQ4 = PQ3 + 13 * HID * HID;      // pack_w2
constexpr int PQ5 = PQ4 + N_NODES * F_INPUT / 4; // cast x (float4)
constexpr int PQ6 = PQ5 + NGRAPH;              // pcnt binary search
constexpr int PREP_BLOCKS = (PQ6 + 255) / 256;

__global__ void prep(const float* __restrict__ Wrel1, const float* __restrict__ root1,
                     const float* __restrict__ Wrel2, const float* __restrict__ root2,
                     const float* __restrict__ x, const int* __restrict__ batch,
                     ushort* __restrict__ Wp1, ushort* __restrict__ Wp2,
                     ushort* __restrict__ xb,
                     float* __restrict__ bn1, float* __restrict__ bn2,
                     float* __restrict__ psum, float* __restrict__ pcnt) {
    int tid = blockIdx.x * 256 + threadIdx.x;
    const uint4 z = make_uint4(0, 0, 0, 0);
    if (tid < PQ0) { reinterpret_cast<uint4*>(bn1)[tid] = z; return; }
    if (tid < PQ1) { reinterpret_cast<uint4*>(bn2)[tid - PQ0] = z; return; }
    if (tid < PQ2) { reinterpret_cast<uint4*>(psum)[tid - PQ1] = z; return; }
    if (tid < PQ3) {
        int idx = tid - PQ2;                       // 13 * 8192
        int r = idx >> 13, rem = idx & 8191;
        int k = rem >> 7, n = rem & 127;
        const float* W = (r < NREL) ? (Wrel1 + (size_t)r * 8192) : root1;
        float v = W[k * HID + n];
        int b = k >> 5, kk = k & 31;
        int j = (n & 7) * 16 + (n >> 3);           // col-permuted fragment row
        Wp1[(((size_t)(r * 2 + b)) * HID + j) * 32 + kk] = (ushort)f2bf(v);
        return;
    }
    if (tid < PQ4) {
        int idx = tid - PQ3;                       // 13 * 16384
        int r = idx >> 14, rem = idx & 16383;
        int k = rem >> 7, n = rem & 127;
        const float* W = (r < NREL) ? (Wrel2 + (size_t)r * 16384) : root2;
        float v = W[k * HID + n];
        int b = k >> 5, kk = k & 31;
        int j = (n & 7) * 16 + (n >> 3);
        Wp2[(((size_t)(r * 4 + b)) * HID + j) * 32 + kk] = (ushort)f2bf(v);
        return;
    }
    if (tid < PQ5) {
        int i = tid - PQ4;
        float4 v = reinterpret_cast<const float4*>(x)[i];
        uint2 o;
        o.x = pack2(v.x, v.y);
        o.y = pack2(v.z, v.w);
        reinterpret_cast<uint2*>(xb)[i] = o;
        return;
    }
    if (tid < PQ6) {
        int g = tid - PQ5;
        int lo0 = 0, hi0 = N_NODES;
        while (lo0 < hi0) { int m = (lo0 + hi0) >> 1; if (batch[m] < g) lo0 = m + 1; else hi0 = m; }
        int lo1 = lo0, hi1 = N_NODES;
        while (lo1 < hi1) { int m = (lo1 + hi1) >> 1; if (batch[m] < g + 1) lo1 = m + 1; else hi1 = m; }
        pcnt[g] = (float)(lo1 - lo0);
    }
}

// ---------------- counting-sort CSR build (no far atomics) ----------------

__global__ __launch_bounds__(PTPB)
void part_hist(const int* __restrict__ dst, int* __restrict__ histG) {
    __shared__ int h[NB];
    int t = threadIdx.x, blk = blockIdx.x;
    if (t < NB) h[t] = 0;
    __syncthreads();
    int base = blk * EPB;
#pragma unroll
    for (int it = 0; it < EPB / PTPB; ++it) {
        int e = base + it * PTPB + t;
        if (e < N_EDGES) atomicAdd(&h[dst[e] >> 7], 1);
    }
    __syncthreads();
    if (t < NB) histG[blk * NB + t] = h[t];
}

__global__ __launch_bounds__(512)
void part_scanA(const int* __restrict__ histG, int* __restrict__ cursorG,
                int* __restrict__ bucketTot) {
    __shared__ int s[512];
    int t = threadIdx.x, b = blockIdx.x;
    int v = (t < NBLK) ? histG[t * NB + b] : 0;
    s[t] = v;
    __syncthreads();
    for (int d = 1; d < 512; d <<= 1) {
        int x = (t >= d) ? s[t - d] : 0;
        __syncthreads();
        s[t] += x;
        __syncthreads();
    }
    if (t < NBLK) cursorG[t * NB + b] = s[t] - v;   // exclusive prefix
    if (t == NBLK - 1) bucketTot[b] = s[t];
}

__global__ __launch_bounds__(512)
void part_scanB(const int* __restrict__ bucketTot, int* __restrict__ bucketBase) {
    __shared__ int s[512];
    int t = threadIdx.x;
    int v = (t < NB) ? bucketTot[t] : 0;
    s[t] = v;
    __syncthreads();
    for (int d = 1; d < 512; d <<= 1) {
        int x = (t >= d) ? s[t - d] : 0;
        __syncthreads();
        s[t] += x;
        __syncthreads();
    }
    if (t <= NB) bucketBase[t] = (t == 0) ? 0 : s[t - 1];
}

__global__ __launch_bounds__(PTPB)
void part_scatter(const int* __restrict__ src, const int* __restrict__ dst,
                  const int* __restrict__ et, const int* __restrict__ cursorG,
                  const int* __restrict__ bucketBase, uint* __restrict__ ebuck) {
    __shared__ int cur[NB];
    int t = threadIdx.x, blk = blockIdx.x;
    if (t < NB) cur[t] = cursorG[blk * NB + t] + bucketBase[t];
    __syncthreads();
    int base = blk * EPB;
#pragma unroll
    for (int it = 0; it < EPB / PTPB; ++it) {
        int e = base + it * PTPB + t;
        if (e < N_EDGES) {
            int d = dst[e];
            int b = d >> 7;
            int pos = atomicAdd(&cur[b], 1);
            ebuck[pos] = (uint)src[e] | ((uint)(d & 127) << 16) | ((uint)et[e] << 23);
        }
    }
}

// P4: per-bucket finalize, REL-MAJOR key: edge list sorted by (bucket, rel, localnode).
// zpack[e] = src | (localnode << 16) -> fused build detects node boundaries
// from the stream itself (no offset pointer-chase in the inner loop).
__global__ __launch_bounds__(256)
void csr_finalize(const uint* __restrict__ ebuck, const int* __restrict__ bucketBase,
                  int* __restrict__ off, uint* __restrict__ zpack) {
    __shared__ int cnt[SEGB];
    __shared__ int cur[SEGB];
    __shared__ int partial[256];
    int t = threadIdx.x, b = blockIdx.x;
    int eb0 = bucketBase[b], eb1 = bucketBase[b + 1];
#pragma unroll
    for (int i = 0; i < 6; ++i) cnt[t * 6 + i] = 0;
    __syncthreads();
    for (int e = eb0 + t; e < eb1; e += 256) {
        uint u = ebuck[e];
        int key = (int)(u >> 23) * 128 + (int)((u >> 16) & 127);   // rel-major
        atomicAdd(&cnt[key], 1);
    }
    __syncthreads();
    int loc[6];
    int sum = 0;
#pragma unroll
    for (int i = 0; i < 6; ++i) { loc[i] = sum; sum += cnt[t * 6 + i]; }
    partial[t] = sum;
    __syncthreads();
    for (int d = 1; d < 256; d <<= 1) {
        int v = (t >= d) ? partial[t - d] : 0;
        __syncthreads();
        partial[t] += v;
        __syncthreads();
    }
    int tbase = (t == 0) ? 0 : partial[t - 1];
#pragma unroll
    for (int i = 0; i < 6; ++i) {
        int s = t * 6 + i;
        int gpos = eb0 + tbase + loc[i];
        cur[s] = gpos;
        off[b * SEGB + s] = gpos;      // all 1536 keys (empty -> zero-length)
    }
    __syncthreads();
    for (int e = eb0 + t; e < eb1; e += 256) {
        uint u = ebuck[e];
        int key = (int)(u >> 23) * 128 + (int)((u >> 16) & 127);
        int pos = atomicAdd(&cur[key], 1);
        zpack[pos] = u & 0x7FFFFFu;                // src(16) | localnode(7)
    }
    if (b == 0 && t == 0) off[NOFF] = N_EDGES;
}

// ---------------- FUSED mean-aggregate + concatenated-K GEMM, in-block rel-split --------
// One block per 16-node STRIP (grid 3125), 4 waves; wave w handles rels
// {3w..3w+2} (wave 3: +root). Plain 8-deep clamped chunks with one-chunk zpack
// prefetch. launch_bounds(256,6) + 17.4 KB LDS keep ~6 waves/SIMD resident.
// Cross-wave combine PAIRWISE in LDS. This is the VERIFIED r6 build
// (471.68 us total, gemm128=164 us @ VALU 49%). Do NOT fuse BN stats into the
// epilogue: r7/r8/r9 all show it collapses VALUBusy 49->11% and 4x's the
// kernel regardless of CH/launch-bounds (mechanism unresolved; empirically toxic).

template <int F>
__global__ __launch_bounds__(256, 6)
void gemm_fused(const ushort* __restrict__ X, const int* __restrict__ offR,
                const uint* __restrict__ zpack, const ushort* __restrict__ Wp,
                const float* __restrict__ bias, float* __restrict__ H) {
    constexpr int FP2 = F + 8;
    constexpr int KB  = F / 32;
    constexpr int CH  = 8;                            // edges per chunk
    constexpr int ABYTES = 4 * 16 * FP2 * 2;          // 4 per-wave A strips
    constexpr int RBYTES = 2 * 16 * HID * 4;          // 16 KB: two fp32 partials
    constexpr int LBYTES = (ABYTES > RBYTES) ? ABYTES : RBYTES;
    __shared__ __align__(16) char LDSU[LBYTES];
    const int t = threadIdx.x;
    const int lane = t & 63, wave = t >> 6, q = lane >> 4, l16 = lane & 15;
    const int strip = blockIdx.x;                      // [0, 3125)
    const int bucket = strip >> 3;
    const int rowbase = (strip & 7) * 16;
    const int n0 = strip * 16;                         // first global node
    const int obase = bucket * SEGB + rowbase;
    ushort* Ab = reinterpret_cast<ushort*>(LDSU) + wave * 16 * FP2;

    auto zerorow = [&](int r) {
        if constexpr (F == 64) Ab[r * FP2 + lane] = 0;
        else *reinterpret_cast<uint*>(Ab + r * FP2 + lane * 2) = 0u;
    };

    auto buildrel = [&](int rel) -> bool {
        const int i0 = obase + rel * 128;
        const int e0 = offR[i0];
        const int e1 = offR[i0 + 16];
        if (e0 >= e1) return false;                     // empty: skip MFMA entirely
        const int elast = e1 - 1;
        float a0 = 0.f, a1 = 0.f;
        int ln = 0, eStart = e0;
        auto flush = [&](int r, int cntE) {
            float winv = (cntE > 0) ? 1.f / (float)cntE : 0.f;
            if constexpr (F == 64)
                Ab[r * FP2 + lane] = (ushort)f2bf(a0 * winv);
            else
                *reinterpret_cast<uint*>(Ab + r * FP2 + lane * 2) = pack2(a0 * winv, a1 * winv);
            a0 = 0.f; a1 = 0.f;
        };
        auto ldpk = [&](int e, uint* p) {
#pragma unroll
            for (int j = 0; j < CH; ++j) p[j] = zpack[min(e + j, elast)];
        };
        uint pk[CH];
        ldpk(e0, pk);
        for (int e = e0; e < e1; e += CH) {
            uint ux[CH];
#pragma unroll
            for (int j = 0; j < CH; ++j) {              // 8 independent gathers
                int s = (int)(pk[j] & 0xFFFFu);
                if constexpr (F == 64)
                    ux[j] = X[(size_t)s * 64 + lane];
                else
                    ux[j] = *reinterpret_cast<const uint*>(X + (size_t)s * 128 + lane * 2);
            }
            uint pkn[CH];
            ldpk(e + CH, pkn);                          // clamped -> always safe
#pragma unroll
            for (int j = 0; j < CH; ++j) {
                int ej = e + j;
                if (ej < e1) {                          // wave-uniform
                    int ld = (int)(pk[j] >> 16) - rowbase;
                    if (ld != ln) {                     // node boundary from stream
                        flush(ln, ej - eStart);
                        for (int z = ln + 1; z < ld; ++z) zerorow(z);
                        ln = ld; eStart = ej;
                    }
                    a0 += bflo(ux[j]);
                    if constexpr (F == 128) a1 += bfhi(ux[j]);
                }
            }
#pragma unroll
            for (int j = 0; j < CH; ++j) pk[j] = pkn[j];
        }
        flush(ln, e1 - eStart);
        for (int z = ln + 1; z < 16; ++z) zerorow(z);
        return true;
    };

    v4f acc[8];
#pragma unroll
    for (int nt = 0; nt < 8; ++nt) acc[nt] = (v4f){0.f, 0.f, 0.f, 0.f};

    const int r0 = wave * 3;
    const int r1 = (wave == 3) ? 13 : (r0 + 3);
    for (int rel = r0; rel < r1; ++rel) {
        bool have;
        if (rel == NREL) {                  // root block: direct copy of X rows
#pragma unroll 4
            for (int i = 0; i < 16; ++i) {
                int n = n0 + i;
                if constexpr (F == 64) {
                    Ab[i * FP2 + lane] = (n < N_NODES) ? X[(size_t)n * 64 + lane] : (ushort)0;
                } else {
                    uint v = (n < N_NODES)
                        ? *reinterpret_cast<const uint*>(X + (size_t)n * 128 + lane * 2) : 0u;
                    *reinterpret_cast<uint*>(Ab + i * FP2 + lane * 2) = v;
                }
            }
            have = true;
        } else {
            have = buildrel(rel);
        }
        if (have) {
#pragma unroll
            for (int kb = 0; kb < KB; ++kb) {
                s8b bfr[8];
                const ushort* wb = Wp + ((size_t)(rel * KB + kb) * HID + l16) * 32 + q * 8;
#pragma unroll
                for (int nt = 0; nt < 8; ++nt)
                    bfr[nt] = *reinterpret_cast<const s8b*>(wb + (size_t)nt * 16 * 32);
                s8b af = *reinterpret_cast<const s8b*>(Ab + l16 * FP2 + kb * 32 + q * 8);
#pragma unroll
                for (int nt = 0; nt < 8; ++nt)
                    acc[nt] = __builtin_amdgcn_mfma_f32_16x16x32_bf16(af, bfr[nt], acc[nt], 0, 0, 0);
            }
        }
    }

    // ---- pairwise cross-wave combine in LDS (A memory dead), wave0 writes H + bias ----
    const int c0 = l16 * 8;    // lane l16 owns logical cols c0..c0+7 (Wp is col-permuted)
    float* red = reinterpret_cast<float*>(LDSU);
    __syncthreads();                       // all MFMA reads of A complete
    if (wave >= 2) {
        float* rw = red + (size_t)(wave - 2) * 16 * HID;
#pragma unroll
        for (int rr = 0; rr < 4; ++rr) {
            int row = q * 4 + rr;
            *reinterpret_cast<float4*>(rw + row * HID + c0) =
                make_float4(acc[0][rr], acc[1][rr], acc[2][rr], acc[3][rr]);
            *reinterpret_cast<float4*>(rw + row * HID + c0 + 4) =
                make_float4(acc[4][rr], acc[5][rr], acc[6][rr], acc[7][rr]);
        }
    }
    __syncthreads();
    if (wave < 2) {
        const float* rw = red + (size_t)wave * 16 * HID;
#pragma unroll
        for (int rr = 0; rr < 4; ++rr) {
            int row = q * 4 + rr;
            float4 a0 = *reinterpret_cast<const float4*>(rw + row * HID + c0);
            float4 a1 = *reinterpret_cast<const float4*>(rw + row * HID + c0 + 4);
            acc[0][rr] += a0.x; acc[1][rr] += a0.y; acc[2][rr] += a0.z; acc[3][rr] += a0.w;
            acc[4][rr] += a1.x; acc[5][rr] += a1.y; acc[6][rr] += a1.z; acc[7][rr] += a1.w;
        }
    }
    __syncthreads();
    if (wave == 1) {
#pragma unroll
        for (int rr = 0; rr < 4; ++rr) {
            int row = q * 4 + rr;
            *reinterpret_cast<float4*>(red + row * HID + c0) =
                make_float4(acc[0][rr], acc[1][rr], acc[2][rr], acc[3][rr]);
            *reinterpret_cast<float4*>(red + row * HID + c0 + 4) =
                make_float4(acc[4][rr], acc[5][rr], acc[6][rr], acc[7][rr]);
        }
    }
    __syncthreads();
    if (wave == 0) {
        float4 b4a = *reinterpret_cast<const float4*>(bias + c0);
        float4 b4b = *reinterpret_cast<const float4*>(bias + c0 + 4);
        float bv[8] = {b4a.x, b4a.y, b4a.z, b4a.w, b4b.x, b4b.y, b4b.z, b4b.w};
#pragma unroll
        for (int rr = 0; rr < 4; ++rr) {
            int row = q * 4 + rr;
            int n = n0 + row;
            if (n < N_NODES) {
                const float* rw = red + row * HID + c0;
                float4 a0 = *reinterpret_cast<const float4*>(rw);
                float4 a1 = *reinterpret_cast<const float4*>(rw + 4);
                float v[8];
                v[0] = acc[0][rr] + a0.x + bv[0];
                v[1] = acc[1][rr] + a0.y + bv[1];
                v[2] = acc[2][rr] + a0.z + bv[2];
                v[3] = acc[3][rr] + a0.w + bv[3];
                v[4] = acc[4][rr] + a1.x + bv[4];
                v[5] = acc[5][rr] + a1.y + bv[5];
                v[6] = acc[6][rr] + a1.z + bv[6];
                v[7] = acc[7][rr] + a1.w + bv[7];
                float* hr = H + (size_t)n * HID + c0;
                *reinterpret_cast<float4*>(hr)     = make_float4(v[0], v[1], v[2], v[3]);
                *reinterpret_cast<float4*>(hr + 4) = make_float4(v[4], v[5], v[6], v[7]);
            }
        }
    }
}

// ---------------- BN statistics over final H ----------------

constexpr int BNS_BLOCKS = 512;
__global__ __launch_bounds__(256)
void bn_stats(const float* __restrict__ H, float* __restrict__ bn) {
    __shared__ float red[2 * HID];
    int t = threadIdx.x;
    red[t] = 0.f;
    __syncthreads();
    float s[4] = {0.f, 0.f, 0.f, 0.f}, sq[4] = {0.f, 0.f, 0.f, 0.f};
    constexpr int TOT4 = N_NODES * HID / 4;
    const int stride = BNS_BLOCKS * 256;       // multiple of 32 -> col group constant
    for (int i = blockIdx.x * 256 + t; i < TOT4; i += stride) {
        float4 v = reinterpret_cast<const float4*>(H)[i];
        s[0] += v.x; s[1] += v.y; s[2] += v.z; s[3] += v.w;
        sq[0] += v.x * v.x; sq[1] += v.y * v.y; sq[2] += v.z * v.z; sq[3] += v.w * v.w;
    }
    int c4 = (t & 31) * 4;
#pragma unroll
    for (int k = 0; k < 4; ++k) {
        atomicAdd(&red[c4 + k], s[k]);
        atomicAdd(&red[HID + c4 + k], sq[k]);
    }
    __syncthreads();
    atomicAdd(&bn[t], red[t]);                 // bn = [sum(128) | sq(128)]
}

// ---------------- BN(+finalize) + ReLU, emit bf16 ----------------

__global__ void bn_relu_bf16(const float* __restrict__ h, const float* __restrict__ bn_sum,
                             const float* __restrict__ bn_sq, const float* __restrict__ gamma,
                             const float* __restrict__ beta, ushort* __restrict__ outb) {
    __shared__ float CA[HID], CB[HID];
    int t = threadIdx.x;
    if (t < HID) {
        float mu = bn_sum[t] * (1.0f / N_NODES);
        float var = bn_sq[t] * (1.0f / N_NODES) - mu * mu;
        float a = gamma[t] / sqrtf(var + BN_EPS);
        CA[t] = a;
        CB[t] = beta[t] - a * mu;
    }
    __syncthreads();
    int i = blockIdx.x * 256 + t;  // float4 index
    constexpr int TOTAL = N_NODES * HID / 4;
    if (i < TOTAL) {
        int o4 = i & 31;
        float4 a = reinterpret_cast<const float4*>(CA)[o4];
        float4 b = reinterpret_cast<const float4*>(CB)[o4];
        float4 v = reinterpret_cast<const float4*>(h)[i];
        v.x = fmaxf(a.x * v.x + b.x, 0.f);
        v.y = fmaxf(a.y * v.y + b.y, 0.f);
        v.z = fmaxf(a.z * v.z + b.z, 0.f);
        v.w = fmaxf(a.w * v.w + b.w, 0.f);
        uint2 o;
        o.x = pack2(v.x, v.y);
        o.y = pack2(v.z, v.w);
        reinterpret_cast<uint2*>(outb)[i] = o;
    }
}

// ---------------- pooling (BN finalize + ReLU fused; batch sorted -> run-length) ----------------

__global__ void pool_bnrelu(const float* __restrict__ h, const float* __restrict__ bn_sum,
                            const float* __restrict__ bn_sq, const float* __restrict__ gamma,
                            const float* __restrict__ beta, const int* __restrict__ batch,
                            float* __restrict__ psum) {
    __shared__ float CA[HID], CB[HID];
    int t = threadIdx.x;
    if (t < HID) {
        float mu = bn_sum[t] * (1.0f / N_NODES);
        float var = bn_sq[t] * (1.0f / N_NODES) - mu * mu;
        float a = gamma[t] / sqrtf(var + BN_EPS);
        CA[t] = a;
        CB[t] = beta[t] - a * mu;
    }
    __syncthreads();
    int col = t & 127;
    int nb = blockIdx.x * 16 + (t >> 7) * 8;  // 8 consecutive nodes per thread
    float a = CA[col], b = CB[col];
    float run = 0.f;
    int curg = -1;
    for (int i = 0; i < 8; ++i) {
        int n = nb + i;
        if (n < N_NODES) {
            int g = batch[n];
            float v = fmaxf(a * h[(size_t)n * HID + col] + b, 0.f);
            if (g != curg) {
                if (curg >= 0) atomicAdd(&psum[curg * HID + col], run);
                run = 0.f;
                curg = g;
            }
            run += v;
        }
    }
    if (curg >= 0) atomicAdd(&psum[curg * HID + col], run);
}

__global__ void final_kernel(const float* __restrict__ psum, const float* __restrict__ pcnt,
                             const float* __restrict__ Wf, const float* __restrict__ bf,
                             float* __restrict__ out) {
    __shared__ float p[HID];
    int g = blockIdx.x, t = threadIdx.x;  // 64 threads
    float inv = 1.0f / fmaxf(pcnt[g], 1.0f);
    p[t] = psum[g * HID + t] * inv;
    p[t + 64] = psum[g * HID + t + 64] * inv;
    __syncthreads();
    if (t < NCLS) {
        float s = bf[t];
#pragma unroll 16
        for (int k = 0; k < HID; ++k) s += p[k] * Wf[k * NCLS + t];
        out[g * NCLS + t] = s;
    }
}

// ---------------- launch ----------------

extern "C" void kernel_launch(void* const* d_in, const int* in_sizes, int n_in,
                              void* d_out, int out_size, void* d_ws, size_t ws_size,
                              hipStream_t stream) {
    const float* x      = (const float*)d_in[0];
    const float* Wrel1  = (const float*)d_in[1];
    const float* root1  = (const float*)d_in[2];
    const float* bias1  = (const float*)d_in[3];
    const float* gamma1 = (const float*)d_in[4];
    const float* beta1  = (const float*)d_in[5];
    const float* Wrel2  = (const float*)d_in[6];
    const float* root2  = (const float*)d_in[7];
    const float* bias2  = (const float*)d_in[8];
    const float* gamma2 = (const float*)d_in[9];
    const float* beta2  = (const float*)d_in[10];
    const float* Wf     = (const float*)d_in[11];
    const float* bf     = (const float*)d_in[12];
    const int* ei       = (const int*)d_in[13];
    const int* et       = (const int*)d_in[14];
    const int* batch    = (const int*)d_in[15];
    const int* srcv = ei;
    const int* dstv = ei + N_EDGES;

    char* w = (char*)d_ws;
    auto alloc = [&](size_t bytes) -> char* {
        char* p = w;
        w += (bytes + 255) / 256 * 256;
        return p;
    };
    int* off     = (int*)alloc((size_t)(NOFF + 1) * 4);        // rel-major segment offsets
    uint* zpack  = (uint*)alloc((size_t)N_EDGES * 4);          // src | localnode<<16
    ushort* xb   = (ushort*)alloc((size_t)N_NODES * F_INPUT * 2);
    ushort* H1b  = (ushort*)alloc((size_t)N_NODES * HID * 2);
    ushort* Wp1  = (ushort*)alloc((size_t)13 * F_INPUT * HID * 2);
    ushort* Wp2  = (ushort*)alloc((size_t)13 * HID * HID * 2);
    float* bn1   = (float*)alloc(2 * HID * 4);  // sum | sq
    float* bn2   = (float*)alloc(2 * HID * 4);
    float* psum  = (float*)alloc((size_t)NGRAPH * HID * 4);
    float* pcnt  = (float*)alloc((size_t)NGRAPH * 4);
    float* Hbuf  = (float*)alloc((size_t)N_NODES * HID * 4);   // H1, later H2
    int* histG      = (int*)alloc((size_t)NBLK * NB * 4);
    int* cursorG    = (int*)alloc((size_t)NBLK * NB * 4);
    int* bucketTot  = (int*)alloc((size_t)NB * 4);
    int* bucketBase = (int*)alloc((size_t)(NB + 1) * 4);
    uint* ebuck     = (uint*)alloc((size_t)N_EDGES * 4);

    prep<<<PREP_BLOCKS, 256, 0, stream>>>(Wrel1, root1, Wrel2, root2, x, batch,
                                          Wp1, Wp2, xb, bn1, bn2, psum, pcnt);

    part_hist<<<NBLK, PTPB, 0, stream>>>(dstv, histG);
    part_scanA<<<NB, 512, 0, stream>>>(histG, cursorG, bucketTot);
    part_scanB<<<1, 512, 0, stream>>>(bucketTot, bucketBase);
    part_scatter<<<NBLK, PTPB, 0, stream>>>(srcv, dstv, et, cursorG, bucketBase, ebuck);
    csr_finalize<<<NB, 256, 0, stream>>>(ebuck, bucketBase, off, zpack);

    // ---- layer 1 (fused aggregate+GEMM, in-block rel-split) ----
    gemm_fused<F_INPUT><<<NSTRIPL, 256, 0, stream>>>(xb, off, zpack, Wp1, bias1, Hbuf);
    bn_stats<<<BNS_BLOCKS, 256, 0, stream>>>(Hbuf, bn1);
    bn_relu_bf16<<<(N_NODES * HID / 4 + 255) / 256, 256, 0, stream>>>(Hbuf, bn1, bn1 + HID,
                                                                      gamma1, beta1, H1b);

    // ---- layer 2 ----
    gemm_fused<HID><<<NSTRIPL, 256, 0, stream>>>(H1b, off, zpack, Wp2, bias2, Hbuf);
    bn_stats<<<BNS_BLOCKS, 256, 0, stream>>>(Hbuf, bn2);

    pool_bnrelu<<<(N_NODES + 15) / 16, 256, 0, stream>>>(Hbuf, bn2, bn2 + HID, gamma2, beta2,
                                                         batch, psum);
    final_kernel<<<NGRAPH, 64, 0, stream>>>(psum, pcnt, Wf, bf, (float*)d_out);
}

// Round 12
// 448.037 us; speedup vs baseline: 3.3393x; 1.0535x over previous
//
#include <hip/hip_runtime.h>

constexpr int N_NODES = 50000;
constexpr int N_EDGES = 1600000;
constexpr int NREL    = 12;
constexpr int F_INPUT = 64;
constexpr int HID     = 128;
constexpr int NCLS    = 10;
constexpr int NGRAPH  = 256;
constexpr float BN_EPS = 1e-5f;

// counting-sort CSR parameters
constexpr int NB    = 391;                    // buckets of 128 nodes (dst >> 7)
constexpr int SEGB  = 128 * NREL;             // 1536 segments per bucket (rel-major)
constexpr int NOFF  = NB * SEGB;              // segment offsets (+1 sentinel)
constexpr int NSTRIPL = 3125;                 // 50000/16 exact strips of 16 nodes
constexpr int NBLK  = 392;                    // partition blocks
constexpr int PTPB  = 1024;
constexpr int EPB   = 4096;                   // edges per partition block (4/thread)

typedef float v4f __attribute__((ext_vector_type(4)));
typedef short s8b __attribute__((ext_vector_type(8)));

__device__ __forceinline__ unsigned f2bf(float f) {
    unsigned u = __float_as_uint(f);
    return (u + 0x7FFFu + ((u >> 16) & 1u)) >> 16;   // RNE fp32->bf16
}
__device__ __forceinline__ unsigned pack2(float a, float b) {
    return f2bf(a) | (f2bf(b) << 16);
}
__device__ __forceinline__ float bflo(unsigned u) { return __uint_as_float(u << 16); }
__device__ __forceinline__ float bfhi(unsigned u) { return __uint_as_float(u & 0xFFFF0000u); }

// ---------------- fused prep: zero scratch + pack weights + cast x + pcnt ----------------
constexpr int PQ0 = 64;                        // bn1: 256 floats (uint4)
constexpr int PQ1 = PQ0 + 64;                  // bn2
constexpr int PQ2 = PQ1 + 8192;                // psum: 32768 floats
constexpr int PQ3 = PQ2 + 13 * F_INPUT * HID;  // pack_w1
constexpr int PQ4 = PQ3 + 13 * HID * HID;      // pack_w2
constexpr int PQ5 = PQ4 + N_NODES * F_INPUT / 4; // cast x (float4)
constexpr int PQ6 = PQ5 + NGRAPH;              // pcnt binary search
constexpr int PREP_BLOCKS = (PQ6 + 255) / 256;

__global__ void prep(const float* __restrict__ Wrel1, const float* __restrict__ root1,
                     const float* __restrict__ Wrel2, const float* __restrict__ root2,
                     const float* __restrict__ x, const int* __restrict__ batch,
                     ushort* __restrict__ Wp1, ushort* __restrict__ Wp2,
                     ushort* __restrict__ xb,
                     float* __restrict__ bn1, float* __restrict__ bn2,
                     float* __restrict__ psum, float* __restrict__ pcnt) {
    int tid = blockIdx.x * 256 + threadIdx.x;
    const uint4 z = make_uint4(0, 0, 0, 0);
    if (tid < PQ0) { reinterpret_cast<uint4*>(bn1)[tid] = z; return; }
    if (tid < PQ1) { reinterpret_cast<uint4*>(bn2)[tid - PQ0] = z; return; }
    if (tid < PQ2) { reinterpret_cast<uint4*>(psum)[tid - PQ1] = z; return; }
    if (tid < PQ3) {
        int idx = tid - PQ2;                       // 13 * 8192
        int r = idx >> 13, rem = idx & 8191;
        int k = rem >> 7, n = rem & 127;
        const float* W = (r < NREL) ? (Wrel1 + (size_t)r * 8192) : root1;
        float v = W[k * HID + n];
        int b = k >> 5, kk = k & 31;
        int j = (n & 7) * 16 + (n >> 3);           // col-permuted fragment row
        Wp1[(((size_t)(r * 2 + b)) * HID + j) * 32 + kk] = (ushort)f2bf(v);
        return;
    }
    if (tid < PQ4) {
        int idx = tid - PQ3;                       // 13 * 16384
        int r = idx >> 14, rem = idx & 16383;
        int k = rem >> 7, n = rem & 127;
        const float* W = (r < NREL) ? (Wrel2 + (size_t)r * 16384) : root2;
        float v = W[k * HID + n];
        int b = k >> 5, kk = k & 31;
        int j = (n & 7) * 16 + (n >> 3);
        Wp2[(((size_t)(r * 4 + b)) * HID + j) * 32 + kk] = (ushort)f2bf(v);
        return;
    }
    if (tid < PQ5) {
        int i = tid - PQ4;
        float4 v = reinterpret_cast<const float4*>(x)[i];
        uint2 o;
        o.x = pack2(v.x, v.y);
        o.y = pack2(v.z, v.w);
        reinterpret_cast<uint2*>(xb)[i] = o;
        return;
    }
    if (tid < PQ6) {
        int g = tid - PQ5;
        int lo0 = 0, hi0 = N_NODES;
        while (lo0 < hi0) { int m = (lo0 + hi0) >> 1; if (batch[m] < g) lo0 = m + 1; else hi0 = m; }
        int lo1 = lo0, hi1 = N_NODES;
        while (lo1 < hi1) { int m = (lo1 + hi1) >> 1; if (batch[m] < g + 1) lo1 = m + 1; else hi1 = m; }
        pcnt[g] = (float)(lo1 - lo0);
    }
}

// ---------------- counting-sort CSR build (no far atomics) ----------------

__global__ __launch_bounds__(PTPB)
void part_hist(const int* __restrict__ dst, int* __restrict__ histG) {
    __shared__ int h[NB];
    int t = threadIdx.x, blk = blockIdx.x;
    if (t < NB) h[t] = 0;
    __syncthreads();
    int base = blk * EPB;
#pragma unroll
    for (int it = 0; it < EPB / PTPB; ++it) {
        int e = base + it * PTPB + t;
        if (e < N_EDGES) atomicAdd(&h[dst[e] >> 7], 1);
    }
    __syncthreads();
    if (t < NB) histG[blk * NB + t] = h[t];
}

__global__ __launch_bounds__(512)
void part_scanA(const int* __restrict__ histG, int* __restrict__ cursorG,
                int* __restrict__ bucketTot) {
    __shared__ int s[512];
    int t = threadIdx.x, b = blockIdx.x;
    int v = (t < NBLK) ? histG[t * NB + b] : 0;
    s[t] = v;
    __syncthreads();
    for (int d = 1; d < 512; d <<= 1) {
        int x = (t >= d) ? s[t - d] : 0;
        __syncthreads();
        s[t] += x;
        __syncthreads();
    }
    if (t < NBLK) cursorG[t * NB + b] = s[t] - v;   // exclusive prefix
    if (t == NBLK - 1) bucketTot[b] = s[t];
}

__global__ __launch_bounds__(512)
void part_scanB(const int* __restrict__ bucketTot, int* __restrict__ bucketBase) {
    __shared__ int s[512];
    int t = threadIdx.x;
    int v = (t < NB) ? bucketTot[t] : 0;
    s[t] = v;
    __syncthreads();
    for (int d = 1; d < 512; d <<= 1) {
        int x = (t >= d) ? s[t - d] : 0;
        __syncthreads();
        s[t] += x;
        __syncthreads();
    }
    if (t <= NB) bucketBase[t] = (t == 0) ? 0 : s[t - 1];
}

__global__ __launch_bounds__(PTPB)
void part_scatter(const int* __restrict__ src, const int* __restrict__ dst,
                  const int* __restrict__ et, const int* __restrict__ cursorG,
                  const int* __restrict__ bucketBase, uint* __restrict__ ebuck) {
    __shared__ int cur[NB];
    int t = threadIdx.x, blk = blockIdx.x;
    if (t < NB) cur[t] = cursorG[blk * NB + t] + bucketBase[t];
    __syncthreads();
    int base = blk * EPB;
#pragma unroll
    for (int it = 0; it < EPB / PTPB; ++it) {
        int e = base + it * PTPB + t;
        if (e < N_EDGES) {
            int d = dst[e];
            int b = d >> 7;
            int pos = atomicAdd(&cur[b], 1);
            ebuck[pos] = (uint)src[e] | ((uint)(d & 127) << 16) | ((uint)et[e] << 23);
        }
    }
}

// P4: per-bucket finalize, REL-MAJOR key: edge list sorted by (bucket, rel, localnode).
// zpack[e] = src | (localnode << 16) -> fused build detects node boundaries
// from the stream itself (no offset pointer-chase in the inner loop).
__global__ __launch_bounds__(256)
void csr_finalize(const uint* __restrict__ ebuck, const int* __restrict__ bucketBase,
                  int* __restrict__ off, uint* __restrict__ zpack) {
    __shared__ int cnt[SEGB];
    __shared__ int cur[SEGB];
    __shared__ int partial[256];
    int t = threadIdx.x, b = blockIdx.x;
    int eb0 = bucketBase[b], eb1 = bucketBase[b + 1];
#pragma unroll
    for (int i = 0; i < 6; ++i) cnt[t * 6 + i] = 0;
    __syncthreads();
    for (int e = eb0 + t; e < eb1; e += 256) {
        uint u = ebuck[e];
        int key = (int)(u >> 23) * 128 + (int)((u >> 16) & 127);   // rel-major
        atomicAdd(&cnt[key], 1);
    }
    __syncthreads();
    int loc[6];
    int sum = 0;
#pragma unroll
    for (int i = 0; i < 6; ++i) { loc[i] = sum; sum += cnt[t * 6 + i]; }
    partial[t] = sum;
    __syncthreads();
    for (int d = 1; d < 256; d <<= 1) {
        int v = (t >= d) ? partial[t - d] : 0;
        __syncthreads();
        partial[t] += v;
        __syncthreads();
    }
    int tbase = (t == 0) ? 0 : partial[t - 1];
#pragma unroll
    for (int i = 0; i < 6; ++i) {
        int s = t * 6 + i;
        int gpos = eb0 + tbase + loc[i];
        cur[s] = gpos;
        off[b * SEGB + s] = gpos;      // all 1536 keys (empty -> zero-length)
    }
    __syncthreads();
    for (int e = eb0 + t; e < eb1; e += 256) {
        uint u = ebuck[e];
        int key = (int)(u >> 23) * 128 + (int)((u >> 16) & 127);
        int pos = atomicAdd(&cur[key], 1);
        zpack[pos] = u & 0x7FFFFFu;                // src(16) | localnode(7)
    }
    if (b == 0 && t == 0) off[NOFF] = N_EDGES;
}

// ---------------- FUSED mean-aggregate + concatenated-K GEMM, in-block rel-split --------
// One block per 16-node STRIP (grid 3125), 4 waves; wave w handles rels
// {3w..3w+2} (wave 3: +root). Plain 8-deep clamped chunks with one-chunk zpack
// prefetch. Cross-wave combine PAIRWISE in LDS. Structure = the VERIFIED r6
// build (471.68 us total, gemm128=164 us @ VALU 49%).
// SINGLE change vs r6: launch_bounds(256,6) -> (256,4). Theory: at lb(,6) the
// allocator budget (~85 regs incl. 32 acc AGPRs) forces walk-state spill ->
// the 66 MB/dispatch of write traffic beyond the 25.6 MB H store. Residency is
// already ~4 blocks/CU, so a 4-wave floor cannot reduce occupancy; it only
// grants the registers to hold pk/pkn/ux without scratch.
// Do NOT fuse BN stats into the epilogue (r7-r9: VALUBusy 49->11%, 4x slower).

template <int F>
__global__ __launch_bounds__(256, 4)
void gemm_fused(const ushort* __restrict__ X, const int* __restrict__ offR,
                const uint* __restrict__ zpack, const ushort* __restrict__ Wp,
                const float* __restrict__ bias, float* __restrict__ H) {
    constexpr int FP2 = F + 8;
    constexpr int KB  = F / 32;
    constexpr int CH  = 8;                            // edges per chunk
    constexpr int ABYTES = 4 * 16 * FP2 * 2;          // 4 per-wave A strips
    constexpr int RBYTES = 2 * 16 * HID * 4;          // 16 KB: two fp32 partials
    constexpr int LBYTES = (ABYTES > RBYTES) ? ABYTES : RBYTES;
    __shared__ __align__(16) char LDSU[LBYTES];
    const int t = threadIdx.x;
    const int lane = t & 63, wave = t >> 6, q = lane >> 4, l16 = lane & 15;
    const int strip = blockIdx.x;                      // [0, 3125)
    const int bucket = strip >> 3;
    const int rowbase = (strip & 7) * 16;
    const int n0 = strip * 16;                         // first global node
    const int obase = bucket * SEGB + rowbase;
    ushort* Ab = reinterpret_cast<ushort*>(LDSU) + wave * 16 * FP2;

    auto zerorow = [&](int r) {
        if constexpr (F == 64) Ab[r * FP2 + lane] = 0;
        else *reinterpret_cast<uint*>(Ab + r * FP2 + lane * 2) = 0u;
    };

    auto buildrel = [&](int rel) -> bool {
        const int i0 = obase + rel * 128;
        const int e0 = offR[i0];
        const int e1 = offR[i0 + 16];
        if (e0 >= e1) return false;                     // empty: skip MFMA entirely
        const int elast = e1 - 1;
        float a0 = 0.f, a1 = 0.f;
        int ln = 0, eStart = e0;
        auto flush = [&](int r, int cntE) {
            float winv = (cntE > 0) ? 1.f / (float)cntE : 0.f;
            if constexpr (F == 64)
                Ab[r * FP2 + lane] = (ushort)f2bf(a0 * winv);
            else
                *reinterpret_cast<uint*>(Ab + r * FP2 + lane * 2) = pack2(a0 * winv, a1 * winv);
            a0 = 0.f; a1 = 0.f;
        };
        auto ldpk = [&](int e, uint* p) {
#pragma unroll
            for (int j = 0; j < CH; ++j) p[j] = zpack[min(e + j, elast)];
        };
        uint pk[CH];
        ldpk(e0, pk);
        for (int e = e0; e < e1; e += CH) {
            uint ux[CH];
#pragma unroll
            for (int j = 0; j < CH; ++j) {              // 8 independent gathers
                int s = (int)(pk[j] & 0xFFFFu);
                if constexpr (F == 64)
                    ux[j] = X[(size_t)s * 64 + lane];
                else
                    ux[j] = *reinterpret_cast<const uint*>(X + (size_t)s * 128 + lane * 2);
            }
            uint pkn[CH];
            ldpk(e + CH, pkn);                          // clamped -> always safe
#pragma unroll
            for (int j = 0; j < CH; ++j) {
                int ej = e + j;
                if (ej < e1) {                          // wave-uniform
                    int ld = (int)(pk[j] >> 16) - rowbase;
                    if (ld != ln) {                     // node boundary from stream
                        flush(ln, ej - eStart);
                        for (int z = ln + 1; z < ld; ++z) zerorow(z);
                        ln = ld; eStart = ej;
                    }
                    a0 += bflo(ux[j]);
                    if constexpr (F == 128) a1 += bfhi(ux[j]);
                }
            }
#pragma unroll
            for (int j = 0; j < CH; ++j) pk[j] = pkn[j];
        }
        flush(ln, e1 - eStart);
        for (int z = ln + 1; z < 16; ++z) zerorow(z);
        return true;
    };

    v4f acc[8];
#pragma unroll
    for (int nt = 0; nt < 8; ++nt) acc[nt] = (v4f){0.f, 0.f, 0.f, 0.f};

    const int r0 = wave * 3;
    const int r1 = (wave == 3) ? 13 : (r0 + 3);
    for (int rel = r0; rel < r1; ++rel) {
        bool have;
        if (rel == NREL) {                  // root block: direct copy of X rows
#pragma unroll 4
            for (int i = 0; i < 16; ++i) {
                int n = n0 + i;
                if constexpr (F == 64) {
                    Ab[i * FP2 + lane] = (n < N_NODES) ? X[(size_t)n * 64 + lane] : (ushort)0;
                } else {
                    uint v = (n < N_NODES)
                        ? *reinterpret_cast<const uint*>(X + (size_t)n * 128 + lane * 2) : 0u;
                    *reinterpret_cast<uint*>(Ab + i * FP2 + lane * 2) = v;
                }
            }
            have = true;
        } else {
            have = buildrel(rel);
        }
        if (have) {
#pragma unroll
            for (int kb = 0; kb < KB; ++kb) {
                s8b bfr[8];
                const ushort* wb = Wp + ((size_t)(rel * KB + kb) * HID + l16) * 32 + q * 8;
#pragma unroll
                for (int nt = 0; nt < 8; ++nt)
                    bfr[nt] = *reinterpret_cast<const s8b*>(wb + (size_t)nt * 16 * 32);
                s8b af = *reinterpret_cast<const s8b*>(Ab + l16 * FP2 + kb * 32 + q * 8);
#pragma unroll
                for (int nt = 0; nt < 8; ++nt)
                    acc[nt] = __builtin_amdgcn_mfma_f32_16x16x32_bf16(af, bfr[nt], acc[nt], 0, 0, 0);
            }
        }
    }

    // ---- pairwise cross-wave combine in LDS (A memory dead), wave0 writes H + bias ----
    const int c0 = l16 * 8;    // lane l16 owns logical cols c0..c0+7 (Wp is col-permuted)
    float* red = reinterpret_cast<float*>(LDSU);
    __syncthreads();                       // all MFMA reads of A complete
    if (wave >= 2) {
        float* rw = red + (size_t)(wave - 2) * 16 * HID;
#pragma unroll
        for (int rr = 0; rr < 4; ++rr) {
            int row = q * 4 + rr;
            *reinterpret_cast<float4*>(rw + row * HID + c0) =
                make_float4(acc[0][rr], acc[1][rr], acc[2][rr], acc[3][rr]);
            *reinterpret_cast<float4*>(rw + row * HID + c0 + 4) =
                make_float4(acc[4][rr], acc[5][rr], acc[6][rr], acc[7][rr]);
        }
    }
    __syncthreads();
    if (wave < 2) {
        const float* rw = red + (size_t)wave * 16 * HID;
#pragma unroll
        for (int rr = 0; rr < 4; ++rr) {
            int row = q * 4 + rr;
            float4 a0 = *reinterpret_cast<const float4*>(rw + row * HID + c0);
            float4 a1 = *reinterpret_cast<const float4*>(rw + row * HID + c0 + 4);
            acc[0][rr] += a0.x; acc[1][rr] += a0.y; acc[2][rr] += a0.z; acc[3][rr] += a0.w;
            acc[4][rr] += a1.x; acc[5][rr] += a1.y; acc[6][rr] += a1.z; acc[7][rr] += a1.w;
        }
    }
    __syncthreads();
    if (wave == 1) {
#pragma unroll
        for (int rr = 0; rr < 4; ++rr) {
            int row = q * 4 + rr;
            *reinterpret_cast<float4*>(red + row * HID + c0) =
                make_float4(acc[0][rr], acc[1][rr], acc[2][rr], acc[3][rr]);
            *reinterpret_cast<float4*>(red + row * HID + c0 + 4) =
                make_float4(acc[4][rr], acc[5][rr], acc[6][rr], acc[7][rr]);
        }
    }
    __syncthreads();
    if (wave == 0) {
        float4 b4a = *reinterpret_cast<const float4*>(bias + c0);
        float4 b4b = *reinterpret_cast<const float4*>(bias + c0 + 4);
        float bv[8] = {b4a.x, b4a.y, b4a.z, b4a.w, b4b.x, b4b.y, b4b.z, b4b.w};
#pragma unroll
        for (int rr = 0; rr < 4; ++rr) {
            int row = q * 4 + rr;
            int n = n0 + row;
            if (n < N_NODES) {
                const float* rw = red + row * HID + c0;
                float4 a0 = *reinterpret_cast<const float4*>(rw);
                float4 a1 = *reinterpret_cast<const float4*>(rw + 4);
                float v[8];
                v[0] = acc[0][rr] + a0.x + bv[0];
                v[1] = acc[1][rr] + a0.y + bv[1];
                v[2] = acc[2][rr] + a0.z + bv[2];
                v[3] = acc[3][rr] + a0.w + bv[3];
                v[4] = acc[4][rr] + a1.x + bv[4];
                v[5] = acc[5][rr] + a1.y + bv[5];
                v[6] = acc[6][rr] + a1.z + bv[6];
                v[7] = acc[7][rr] + a1.w + bv[7];
                float* hr = H + (size_t)n * HID + c0;
                *reinterpret_cast<float4*>(hr)     = make_float4(v[0], v[1], v[2], v[3]);
                *reinterpret_cast<float4*>(hr + 4) = make_float4(v[4], v[5], v[6], v[7]);
            }
        }
    }
}

// ---------------- BN statistics over final H ----------------

constexpr int BNS_BLOCKS = 512;
__global__ __launch_bounds__(256)
void bn_stats(const float* __restrict__ H, float* __restrict__ bn) {
    __shared__ float red[2 * HID];
    int t = threadIdx.x;
    red[t] = 0.f;
    __syncthreads();
    float s[4] = {0.f, 0.f, 0.f, 0.f}, sq[4] = {0.f, 0.f, 0.f, 0.f};
    constexpr int TOT4 = N_NODES * HID / 4;
    const int stride = BNS_BLOCKS * 256;       // multiple of 32 -> col group constant
    for (int i = blockIdx.x * 256 + t; i < TOT4; i += stride) {
        float4 v = reinterpret_cast<const float4*>(H)[i];
        s[0] += v.x; s[1] += v.y; s[2] += v.z; s[3] += v.w;
        sq[0] += v.x * v.x; sq[1] += v.y * v.y; sq[2] += v.z * v.z; sq[3] += v.w * v.w;
    }
    int c4 = (t & 31) * 4;
#pragma unroll
    for (int k = 0; k < 4; ++k) {
        atomicAdd(&red[c4 + k], s[k]);
        atomicAdd(&red[HID + c4 + k], sq[k]);
    }
    __syncthreads();
    atomicAdd(&bn[t], red[t]);                 // bn = [sum(128) | sq(128)]
}

// ---------------- BN(+finalize) + ReLU, emit bf16 ----------------

__global__ void bn_relu_bf16(const float* __restrict__ h, const float* __restrict__ bn_sum,
                             const float* __restrict__ bn_sq, const float* __restrict__ gamma,
                             const float* __restrict__ beta, ushort* __restrict__ outb) {
    __shared__ float CA[HID], CB[HID];
    int t = threadIdx.x;
    if (t < HID) {
        float mu = bn_sum[t] * (1.0f / N_NODES);
        float var = bn_sq[t] * (1.0f / N_NODES) - mu * mu;
        float a = gamma[t] / sqrtf(var + BN_EPS);
        CA[t] = a;
        CB[t] = beta[t] - a * mu;
    }
    __syncthreads();
    int i = blockIdx.x * 256 + t;  // float4 index
    constexpr int TOTAL = N_NODES * HID / 4;
    if (i < TOTAL) {
        int o4 = i & 31;
        float4 a = reinterpret_cast<const float4*>(CA)[o4];
        float4 b = reinterpret_cast<const float4*>(CB)[o4];
        float4 v = reinterpret_cast<const float4*>(h)[i];
        v.x = fmaxf(a.x * v.x + b.x, 0.f);
        v.y = fmaxf(a.y * v.y + b.y, 0.f);
        v.z = fmaxf(a.z * v.z + b.z, 0.f);
        v.w = fmaxf(a.w * v.w + b.w, 0.f);
        uint2 o;
        o.x = pack2(v.x, v.y);
        o.y = pack2(v.z, v.w);
        reinterpret_cast<uint2*>(outb)[i] = o;
    }
}

// ---------------- pooling (BN finalize + ReLU fused; batch sorted -> run-length) ----------------

__global__ void pool_bnrelu(const float* __restrict__ h, const float* __restrict__ bn_sum,
                            const float* __restrict__ bn_sq, const float* __restrict__ gamma,
                            const float* __restrict__ beta, const int* __restrict__ batch,
                            float* __restrict__ psum) {
    __shared__ float CA[HID], CB[HID];
    int t = threadIdx.x;
    if (t < HID) {
        float mu = bn_sum[t] * (1.0f / N_NODES);
        float var = bn_sq[t] * (1.0f / N_NODES) - mu * mu;
        float a = gamma[t] / sqrtf(var + BN_EPS);
        CA[t] = a;
        CB[t] = beta[t] - a * mu;
    }
    __syncthreads();
    int col = t & 127;
    int nb = blockIdx.x * 16 + (t >> 7) * 8;  // 8 consecutive nodes per thread
    float a = CA[col], b = CB[col];
    float run = 0.f;
    int curg = -1;
    for (int i = 0; i < 8; ++i) {
        int n = nb + i;
        if (n < N_NODES) {
            int g = batch[n];
            float v = fmaxf(a * h[(size_t)n * HID + col] + b, 0.f);
            if (g != curg) {
                if (curg >= 0) atomicAdd(&psum[curg * HID + col], run);
                run = 0.f;
                curg = g;
            }
            run += v;
        }
    }
    if (curg >= 0) atomicAdd(&psum[curg * HID + col], run);
}

__global__ void final_kernel(const float* __restrict__ psum, const float* __restrict__ pcnt,
                             const float* __restrict__ Wf, const float* __restrict__ bf,
                             float* __restrict__ out) {
    __shared__ float p[HID];
    int g = blockIdx.x, t = threadIdx.x;  // 64 threads
    float inv = 1.0f / fmaxf(pcnt[g], 1.0f);
    p[t] = psum[g * HID + t] * inv;
    p[t + 64] = psum[g * HID + t + 64] * inv;
    __syncthreads();
    if (t < NCLS) {
        float s = bf[t];
#pragma unroll 16
        for (int k = 0; k < HID; ++k) s += p[k] * Wf[k * NCLS + t];
        out[g * NCLS + t] = s;
    }
}

// ---------------- launch ----------------

extern "C" void kernel_launch(void* const* d_in, const int* in_sizes, int n_in,
                              void* d_out, int out_size, void* d_ws, size_t ws_size,
                              hipStream_t stream) {
    const float* x      = (const float*)d_in[0];
    const float* Wrel1  = (const float*)d_in[1];
    const float* root1  = (const float*)d_in[2];
    const float* bias1  = (const float*)d_in[3];
    const float* gamma1 = (const float*)d_in[4];
    const float* beta1  = (const float*)d_in[5];
    const float* Wrel2  = (const float*)d_in[6];
    const float* root2  = (const float*)d_in[7];
    const float* bias2  = (const float*)d_in[8];
    const float* gamma2 = (const float*)d_in[9];
    const float* beta2  = (const float*)d_in[10];
    const float* Wf     = (const float*)d_in[11];
    const float* bf     = (const float*)d_in[12];
    const int* ei       = (const int*)d_in[13];
    const int* et       = (const int*)d_in[14];
    const int* batch    = (const int*)d_in[15];
    const int* srcv = ei;
    const int* dstv = ei + N_EDGES;

    char* w = (char*)d_ws;
    auto alloc = [&](size_t bytes) -> char* {
        char* p = w;
        w += (bytes + 255) / 256 * 256;
        return p;
    };
    int* off     = (int*)alloc((size_t)(NOFF + 1) * 4);        // rel-major segment offsets
    uint* zpack  = (uint*)alloc((size_t)N_EDGES * 4);          // src | localnode<<16
    ushort* xb   = (ushort*)alloc((size_t)N_NODES * F_INPUT * 2);
    ushort* H1b  = (ushort*)alloc((size_t)N_NODES * HID * 2);
    ushort* Wp1  = (ushort*)alloc((size_t)13 * F_INPUT * HID * 2);
    ushort* Wp2  = (ushort*)alloc((size_t)13 * HID * HID * 2);
    float* bn1   = (float*)alloc(2 * HID * 4);  // sum | sq
    float* bn2   = (float*)alloc(2 * HID * 4);
    float* psum  = (float*)alloc((size_t)NGRAPH * HID * 4);
    float* pcnt  = (float*)alloc((size_t)NGRAPH * 4);
    float* Hbuf  = (float*)alloc((size_t)N_NODES * HID * 4);   // H1, later H2
    int* histG      = (int*)alloc((size_t)NBLK * NB * 4);
    int* cursorG    = (int*)alloc((size_t)NBLK * NB * 4);
    int* bucketTot  = (int*)alloc((size_t)NB * 4);
    int* bucketBase = (int*)alloc((size_t)(NB + 1) * 4);
    uint* ebuck     = (uint*)alloc((size_t)N_EDGES * 4);

    prep<<<PREP_BLOCKS, 256, 0, stream>>>(Wrel1, root1, Wrel2, root2, x, batch,
                                          Wp1, Wp2, xb, bn1, bn2, psum, pcnt);

    part_hist<<<NBLK, PTPB, 0, stream>>>(dstv, histG);
    part_scanA<<<NB, 512, 0, stream>>>(histG, cursorG, bucketTot);
    part_scanB<<<1, 512, 0, stream>>>(bucketTot, bucketBase);
    part_scatter<<<NBLK, PTPB, 0, stream>>>(srcv, dstv, et, cursorG, bucketBase, ebuck);
    csr_finalize<<<NB, 256, 0, stream>>>(ebuck, bucketBase, off, zpack);

    // ---- layer 1 (fused aggregate+GEMM, in-block rel-split) ----
    gemm_fused<F_INPUT><<<NSTRIPL, 256, 0, stream>>>(xb, off, zpack, Wp1, bias1, Hbuf);
    bn_stats<<<BNS_BLOCKS, 256, 0, stream>>>(Hbuf, bn1);
    bn_relu_bf16<<<(N_NODES * HID / 4 + 255) / 256, 256, 0, stream>>>(Hbuf, bn1, bn1 + HID,
                                                                      gamma1, beta1, H1b);

    // ---- layer 2 ----
    gemm_fused<HID><<<NSTRIPL, 256, 0, stream>>>(H1b, off, zpack, Wp2, bias2, Hbuf);
    bn_stats<<<BNS_BLOCKS, 256, 0, stream>>>(Hbuf, bn2);

    pool_bnrelu<<<(N_NODES + 15) / 16, 256, 0, stream>>>(Hbuf, bn2, bn2 + HID, gamma2, beta2,
                                                         batch, psum);
    final_kernel<<<NGRAPH, 64, 0, stream>>>(psum, pcnt, Wf, bf, (float*)d_out);
}